// Round 9
// baseline (1529.553 us; speedup 1.0000x reference)
//
#include <hip/hip_runtime.h>

// B=128, T=48, I=128, H=512. Sequential 48-step attention+GRU scan.
// R9 = R8 with the s_sleep constant-arg compile fix.
// Cross-block data flows through STEP-INDEXED ROTATING buffers: producers
// write with agent-scope sc stores (write-through to MALL, proven R3-R5),
// consumers read with NORMAL CACHED loads — safe because rotated addresses
// are never cached before their first post-barrier read (L2 invalidated at
// launch; addresses unique within launch), and the first miss fills the local
// L2 so sibling blocks hit. Barrier: one monotone counter per group, RMW
// arrival, SINGLE-lane poll with s_sleep backoff -> ~10 GB/s poll traffic,
// no fabric self-congestion (the R5 failure mode).
// Band-aligned col-split keeps gh (z cols 512..2047) entirely block-local.

typedef _Float16 half8 __attribute__((ext_vector_type(8)));
typedef _Float16 h2v  __attribute__((ext_vector_type(2)));
typedef float    f32x4 __attribute__((ext_vector_type(4)));

// ---------------- ws layout (bytes) ----------------
#define OFF_BAR   0u          // 8 group counters, 128B apart (zeroed by prep)
#define OFF_BZ    32768u      // 2048 f32 : [b1 ; b_hh]
#define OFF_BC    40960u      // 1536 f32 : W_ih@b4 + b_ih
#define OFF_WZ    65536u      // 2048*512 f16 : [W1 ; W_hh] row-major
#define OFF_WCT   2162688u    // 131*1536 f16 : (W_ih@W4)^T, k-major
#define OFF_W2H   2621440u    // 128*48*512 f16 : dx@W2^T + b2
#define OFF_HB    8912896u    // 49 slots x 128*512 f16 : rotating h
#define OFF_W1R   15335424u   // 48 slots x 128*512 f16 : rotating w1
#define OFF_YR    21626880u   // 48 slots x 128*132 f32 : rotating y
// total ~23.7 MB

__device__ __forceinline__ float fexp2(float x) { return __builtin_amdgcn_exp2f(x); }
__device__ __forceinline__ float frcp(float x)  { return __builtin_amdgcn_rcpf(x); }
__device__ __forceinline__ float fast_tanh(float x) {
  x = fminf(fmaxf(x, -15.f), 15.f);
  float e = fexp2(x * 2.8853900817779268f);
  return (e - 1.f) * frcp(e + 1.f);
}
__device__ __forceinline__ float fast_sigmoid(float x) {
  x = fminf(fmaxf(x, -30.f), 30.f);
  float e = fexp2(x * 1.4426950408889634f);
  return e * frcp(e + 1.f);
}

union HU { unsigned int u; h2v h; };
union H4 { unsigned long long u; _Float16 h[4]; };

// sc (agent-scope) stores: write-through to MALL (coherence point)
__device__ __forceinline__ void sc_f32(float* p, float v) {
  __hip_atomic_store(p, v, __ATOMIC_RELAXED, __HIP_MEMORY_SCOPE_AGENT);
}
__device__ __forceinline__ void sc_u16(unsigned short* p, unsigned short v) {
  __hip_atomic_store(p, v, __ATOMIC_RELAXED, __HIP_MEMORY_SCOPE_AGENT);
}
__device__ __forceinline__ void sc_u32(unsigned int* p, unsigned int v) {
  __hip_atomic_store(p, v, __ATOMIC_RELAXED, __HIP_MEMORY_SCOPE_AGENT);
}

// Monotone-counter group barrier. __syncthreads() drains vmcnt (sc stores
// acked at MALL) before the arrival RMW. Poll: ONE lane, ONE 64B line,
// sleep-backoff -> no fabric congestion. Bounded (finite-wrong > hang).
__device__ __forceinline__ void grp_barrier(unsigned int* ctr, unsigned int target) {
  __syncthreads();
  if (threadIdx.x == 0) {
    __hip_atomic_fetch_add(ctr, 1u, __ATOMIC_RELAXED, __HIP_MEMORY_SCOPE_AGENT);
    int it = 0;
    while (__hip_atomic_load(ctr, __ATOMIC_RELAXED, __HIP_MEMORY_SCOPE_AGENT) < target) {
      if (it < 8) { __builtin_amdgcn_s_sleep(4); }
      else        { __builtin_amdgcn_s_sleep(32); }
      if (++it > (1 << 16)) break;
    }
    __asm__ __volatile__("" ::: "memory");
  }
  __syncthreads();
}

// ---------------- fused prep kernel (grid 322 x 256) ----------------
__global__ __launch_bounds__(256) void prep_all(
    const float* __restrict__ dx, const float* __restrict__ h0,
    const float* __restrict__ W1, const float* __restrict__ Whh,
    const float* __restrict__ b1, const float* __restrict__ bhh,
    const float* __restrict__ Wih, const float* __restrict__ W4,
    const float* __restrict__ b4, const float* __restrict__ bih,
    const float* __restrict__ W2, const float* __restrict__ b2,
    _Float16* __restrict__ hb0,
    _Float16* __restrict__ Wzh, float* __restrict__ bz,
    float* __restrict__ bc, _Float16* __restrict__ WcT,
    _Float16* __restrict__ w2h, unsigned int* __restrict__ bar)
{
  __shared__ __align__(16) char smem[58368];
  const int bid = blockIdx.x;
  const int tid = threadIdx.x;
  const int lane = tid & 63, wv = tid >> 6;

  if (bid == 0) {                       // zero barrier counters
    for (int i = tid; i < 1024; i += 256) bar[i] = 0u;
  } else if (bid == 1) {                // bz
    for (int n = tid; n < 2048; n += 256)
      bz[n] = (n < 512) ? b1[n] : bhh[n - 512];
  } else if (bid < 18) {                // bc: 16 blocks x 96 rows, wave/row
    const int o0 = (bid - 2) * 96 + wv * 24;
    for (int it = 0; it < 24; ++it) {
      const int row = o0 + it;
      const float* r = Wih + row * 512 + lane * 8;
      float s = 0.f;
#pragma unroll
      for (int u = 0; u < 8; ++u) s += r[u] * b4[lane * 8 + u];
#pragma unroll
      for (int off = 32; off >= 1; off >>= 1) s += __shfl_xor(s, off);
      if (lane == 0) bc[row] = bih[row] + s;
    }
  } else if (bid < 34) {                // hbuf slot 0 = f16(h0)
    const int i0 = (bid - 18) * 4096 + tid * 16;
#pragma unroll
    for (int u = 0; u < 4; ++u) {
      float4 v = *(const float4*)(h0 + i0 + u * 4);
      H4 p; p.h[0] = (_Float16)v.x; p.h[1] = (_Float16)v.y;
      p.h[2] = (_Float16)v.z; p.h[3] = (_Float16)v.w;
      *(unsigned long long*)(hb0 + i0 + u * 4) = p.u;
    }
  } else if (bid < 98) {                // Wzh = f16([W1;Whh]) flat copy
    const int i0 = (bid - 34) * 16384 + tid * 64;
#pragma unroll 4
    for (int u = 0; u < 16; ++u) {
      const int i = i0 + u * 4;
      const float* src = (i < 262144) ? (W1 + i) : (Whh + i - 262144);
      float4 v = *(const float4*)src;
      H4 p; p.h[0] = (_Float16)v.x; p.h[1] = (_Float16)v.y;
      p.h[2] = (_Float16)v.z; p.h[3] = (_Float16)v.w;
      *(unsigned long long*)(Wzh + i) = p.u;
    }
  } else if (bid < 194) {               // WcT[k][o] = (Wih@W4)[o][k]
    float* wih = (float*)smem;
    float* w4s = (float*)(smem + 4224);
    const int o0 = (bid - 98) * 16;
    const int k = tid;
    float acc[16];
#pragma unroll
    for (int i = 0; i < 16; ++i) acc[i] = 0.f;
    for (int jc = 0; jc < 512; jc += 64) {
      __syncthreads();
      for (int idx = tid; idx < 16 * 64; idx += 256) {
        int oo = idx >> 6, jj = idx & 63;
        wih[oo * 66 + jj] = Wih[(o0 + oo) * 512 + jc + jj];
      }
      for (int idx = tid; idx < 64 * 131; idx += 256) {
        int r = idx / 131, c = idx - r * 131;
        w4s[r * 132 + c] = W4[(jc + r) * 131 + c];
      }
      __syncthreads();
      if (k < 131) {
        for (int jj = 0; jj < 64; ++jj) {
          float w4v = w4s[jj * 132 + k];
#pragma unroll
          for (int oo = 0; oo < 16; ++oo) acc[oo] += wih[oo * 66 + jj] * w4v;
        }
      }
    }
    if (k < 131) {
#pragma unroll
      for (int oo = 0; oo < 16; ++oo)
        WcT[k * 1536 + o0 + oo] = (_Float16)acc[oo];
    }
  } else {                              // w2h: 128 blocks, one batch row each
    float* dxa = (float*)smem;
    _Float16* w2t = (_Float16*)(smem + 24576);
    const int b = bid - 194;
    for (int idx = tid; idx < 48 * 128; idx += 256)
      dxa[idx] = dx[b * 6144 + idx];
    for (int hc = 0; hc < 4; ++hc) {
      __syncthreads();
      for (int idx = tid; idx < 128 * 128; idx += 256) {
        int hl = idx >> 7, i = idx & 127;
        w2t[i * 132 + hl] = (_Float16)W2[(hc * 128 + hl) * 128 + i];
      }
      __syncthreads();
      const int hh = tid & 127;
      const int tq = tid >> 7;
      const float b2v = b2[hc * 128 + hh];
      for (int tt = tq * 24; tt < tq * 24 + 24; ++tt) {
        float acc = b2v;
#pragma unroll 4
        for (int i = 0; i < 128; ++i)
          acc += dxa[tt * 128 + i] * (float)w2t[i * 132 + hh];
        w2h[(b * 48 + tt) * 512 + hc * 128 + hh] = (_Float16)acc;
      }
    }
  }
}

// ---------------- main persistent scan kernel ----------------
__global__ __launch_bounds__(256, 1) void decoder_main(
    const float* __restrict__ dx, const float* __restrict__ xin,
    const float* __restrict__ h0,
    const float* __restrict__ W3, const float* __restrict__ b3,
    const float* __restrict__ Wfc, const float* __restrict__ bfc,
    const _Float16* __restrict__ Wzh, const float* __restrict__ bz,
    const _Float16* __restrict__ WcT, const float* __restrict__ bc,
    const _Float16* __restrict__ w2h,
    _Float16* __restrict__ hbuf, _Float16* __restrict__ w1rot,
    float* __restrict__ yrot,
    unsigned int* __restrict__ bar, float* __restrict__ out)
{
  const int tid  = threadIdx.x;
  const int lane = tid & 63;
  const int wv   = tid >> 6;
  const int bid  = blockIdx.x;
  const int grp  = bid & 7;      // XCD-locality heuristic only (not correctness)
  const int mem  = bid >> 3;     // 0..15
  const int b0   = grp * 16;     // group batch rows [b0, b0+16)
  const int myrow = b0 + mem;    // ph2 row
  const int c0b  = mem * 32;     // block's 32-col h band
  unsigned int* ctr = bar + grp * 32;
  unsigned int sync_no = 0;

  __shared__ float ghs[16][100];     // gh bands (3x32 per row), block-local
  __shared__ float ygs[16][132];
  __shared__ float es[48];
  __shared__ float asx[48];
  __shared__ float wfcs[512];
  __shared__ float red[4];

  // ---- persistent per-lane state ----
  const int m = lane & 15, q = lane >> 4;
  // ph1 weights in registers: wave wv owns band wv (z-cols wv*512 + c0b + [0,32))
  half8 wzf[2][16];
  float bzv[2];
#pragma unroll
  for (int t = 0; t < 2; ++t) {
    const int n = wv * 512 + c0b + t * 16 + m;
    const _Float16* wrow = Wzh + n * 512 + q * 8;
#pragma unroll
    for (int ks = 0; ks < 16; ++ks)
      wzf[t][ks] = *(const half8*)(wrow + ks * 32);
    bzv[t] = bz[n];
  }
  float w3r[8];
#pragma unroll
  for (int u = 0; u < 8; ++u) w3r[u] = W3[lane * 8 + u];
  for (int i = tid; i < 512; i += 256) wfcs[i] = Wfc[i];
  const float b3v  = b3[0];
  const float bfcv = bfc[0];
  // ph3 ownership: thread (m3, cg) -> row b0+m3, h-cols c0 = c0b + cg*2
  const int m3 = tid >> 4;
  const int cg = tid & 15;
  const int c0 = c0b + cg * 2;
  const float bc0 = bc[c0],        bc1 = bc[c0 + 1];
  const float bc2 = bc[512 + c0],  bc3 = bc[512 + c0 + 1];
  const float bc4 = bc[1024 + c0], bc5 = bc[1024 + c0 + 1];
  float hA = h0[(b0 + m3) * 512 + c0];      // fp32 h master in registers
  float hB = h0[(b0 + m3) * 512 + c0 + 1];

  for (int step = 0; step < 48; ++step) {
    const _Float16* hstep = hbuf + (size_t)step * 65536;        // rotating
    _Float16* w1s_ = w1rot + (size_t)step * 65536;
    float*    ys_  = yrot + (size_t)step * 16896;
    _Float16* hnext = hbuf + (size_t)(step + 1) * 65536;

    // ---- ph1: z cols {b*512+c0b+[0,32)} = h @ Wz^T + bz  (MFMA, reg weights)
    //      band 0 (w1) -> rotating w1 buffer (sc f16); bands 1-3 (gh) -> LDS
    {
      const _Float16* hrow = hstep + (b0 + m) * 512 + q * 8;    // NORMAL loads
      half8 af[16];
#pragma unroll
      for (int ks = 0; ks < 16; ++ks)
        af[ks] = *(const half8*)(hrow + ks * 32);
#pragma unroll
      for (int t = 0; t < 2; ++t) {
        f32x4 acc = {bzv[t], bzv[t], bzv[t], bzv[t]};
#pragma unroll
        for (int ks = 0; ks < 16; ++ks)
          acc = __builtin_amdgcn_mfma_f32_16x16x32_f16(af[ks], wzf[t][ks], acc, 0, 0, 0);
        const int cl = c0b + t * 16 + m;          // column within band
        if (wv == 0) {
#pragma unroll
          for (int r = 0; r < 4; ++r) {
            _Float16 hv = (_Float16)acc[r];
            sc_u16((unsigned short*)(w1s_ + (b0 + q * 4 + r) * 512 + cl),
                   *(unsigned short*)&hv);
          }
        } else {
#pragma unroll
          for (int r = 0; r < 4; ++r)
            ghs[q * 4 + r][(wv - 1) * 32 + t * 16 + m] = acc[r];
        }
      }
    }
    ++sync_no; grp_barrier(ctr, 16u * sync_no);     // w1 ready

    // ---- ph2: attention for own row (normal cached reads of w1) ----
    {
      const _Float16* w1row = w1s_ + myrow * 512 + lane * 8;
      half8 w1v8 = *(const half8*)w1row;
      float w1r[8];
#pragma unroll
      for (int u = 0; u < 8; ++u) w1r[u] = (float)w1v8[u];
      const _Float16* __restrict__ w2row = w2h + myrow * 48 * 512 + lane * 8;
      for (int tt = 0; tt < 12; ++tt) {
        const int t = wv * 12 + tt;
        half8 w2v = *(const half8*)(w2row + t * 512);
        float p = 0.f;
#pragma unroll
        for (int u = 0; u < 8; ++u)
          p += w3r[u] * fast_tanh(w1r[u] + (float)w2v[u]);
#pragma unroll
        for (int off = 32; off >= 1; off >>= 1) p += __shfl_xor(p, off);
        if (lane == 0) es[t] = p + b3v;
      }
      __syncthreads();
      if (wv == 0) {
        float e = (lane < 48) ? es[lane] : -1e30f;
        float mx = e;
#pragma unroll
        for (int off = 32; off >= 1; off >>= 1) mx = fmaxf(mx, __shfl_xor(mx, off));
        float pe = (lane < 48) ? fexp2((e - mx) * 1.4426950408889634f) : 0.f;
        float s = pe;
#pragma unroll
        for (int off = 32; off >= 1; off >>= 1) s += __shfl_xor(s, off);
        float a = pe * frcp(s);
        if (lane < 48) {
          asx[lane] = a;
          if (step == 47) out[128 + myrow * 48 + lane] = a;   // alpha
        }
      }
      __syncthreads();
      if (tid < 128) {
        float acc = 0.f;
        const float* __restrict__ dxr = dx + myrow * 6144 + tid;
#pragma unroll 4
        for (int t = 0; t < 48; ++t) acc += asx[t] * dxr[t * 128];
        sc_f32(&ys_[myrow * 132 + tid], acc);                 // c
      } else if (tid < 131) {
        sc_f32(&ys_[myrow * 132 + tid], xin[(myrow * 48 + step) * 3 + (tid - 128)]);
      }
    }
    ++sync_no; grp_barrier(ctr, 16u * sync_no);     // y ready

    // ---- ph3: gi = y@Wc^T + bc (own 96 of 1536 cols, all 16 rows);
    //      gates use block-local gh (LDS) + reg h; h_new -> rotating hbuf ----
    {
      for (int i = tid; i < 16 * 66; i += 256) {     // stage y (normal reads)
        int r = i / 66, c = (i - r * 66) * 2;
        float2 v = *(const float2*)(ys_ + (b0 + r) * 132 + c);
        ygs[r][c] = v.x; ygs[r][c + 1] = v.y;
      }
      __syncthreads();
      float a0 = bc0, a1 = bc1, a2 = bc2, a3 = bc3, a4 = bc4, a5 = bc5;
      const float* __restrict__ yrow = ygs[m3];
#pragma unroll 4
      for (int k = 0; k < 131; ++k) {
        const float yk = yrow[k];
        const _Float16* __restrict__ wr = WcT + k * 1536 + c0;
        h2v w0 = *(const h2v*)(wr);
        h2v w1v = *(const h2v*)(wr + 512);
        h2v w2v = *(const h2v*)(wr + 1024);
        a0 += yk * (float)w0[0];  a1 += yk * (float)w0[1];
        a2 += yk * (float)w1v[0]; a3 += yk * (float)w1v[1];
        a4 += yk * (float)w2v[0]; a5 += yk * (float)w2v[1];
      }
      const int cl = cg * 2;
      const float hr0 = ghs[m3][cl],      hr1 = ghs[m3][cl + 1];
      const float hz0 = ghs[m3][32 + cl], hz1 = ghs[m3][32 + cl + 1];
      const float hn0 = ghs[m3][64 + cl], hn1 = ghs[m3][64 + cl + 1];
      const float r0 = fast_sigmoid(a0 + hr0), r1 = fast_sigmoid(a1 + hr1);
      const float z0 = fast_sigmoid(a2 + hz0), z1 = fast_sigmoid(a3 + hz1);
      const float n0 = fast_tanh(a4 + r0 * hn0), n1 = fast_tanh(a5 + r1 * hn1);
      hA = (1.f - z0) * n0 + z0 * hA;
      hB = (1.f - z1) * n1 + z1 * hB;
      HU hp; hp.h[0] = (_Float16)hA; hp.h[1] = (_Float16)hB;
      sc_u32((unsigned int*)(hnext + (b0 + m3) * 512 + c0), hp.u);
    }
    ++sync_no; grp_barrier(ctr, 16u * sync_no);     // h ready
  }

  // ---- epilogue: re[myrow] = h_f . Wfc + bfc  (normal reads of hbuf[48]) ----
  {
    const _Float16* hf = hbuf + (size_t)48 * 65536 + myrow * 512;
    HU hu; hu.u = *(const unsigned int*)(hf + tid * 2);
    float p = (float)hu.h[0] * wfcs[2 * tid] + (float)hu.h[1] * wfcs[2 * tid + 1];
#pragma unroll
    for (int off = 32; off >= 1; off >>= 1) p += __shfl_xor(p, off);
    if (lane == 0) red[wv] = p;
    __syncthreads();
    if (tid == 0) out[myrow] = red[0] + red[1] + red[2] + red[3] + bfcv;
  }
}

extern "C" void kernel_launch(void* const* d_in, const int* in_sizes, int n_in,
                              void* d_out, int out_size, void* d_ws, size_t ws_size,
                              hipStream_t stream) {
  (void)in_sizes; (void)n_in; (void)out_size; (void)ws_size;
  const float* dx  = (const float*)d_in[0];
  const float* xin = (const float*)d_in[1];
  const float* h0  = (const float*)d_in[2];
  const float* W1  = (const float*)d_in[3];
  const float* b1  = (const float*)d_in[4];
  const float* W2  = (const float*)d_in[5];
  const float* b2  = (const float*)d_in[6];
  const float* W3  = (const float*)d_in[7];
  const float* b3  = (const float*)d_in[8];
  const float* W4  = (const float*)d_in[9];
  const float* b4  = (const float*)d_in[10];
  const float* Wih = (const float*)d_in[11];
  const float* Whh = (const float*)d_in[12];
  const float* bih = (const float*)d_in[13];
  const float* bhh = (const float*)d_in[14];
  const float* Wfc = (const float*)d_in[15];
  const float* bfc = (const float*)d_in[16];

  char* ws = (char*)d_ws;
  unsigned int* bar = (unsigned int*)(ws + OFF_BAR);
  float*     bz   = (float*)(ws + OFF_BZ);
  float*     bc   = (float*)(ws + OFF_BC);
  _Float16*  Wzh  = (_Float16*)(ws + OFF_WZ);
  _Float16*  WcT  = (_Float16*)(ws + OFF_WCT);
  _Float16*  w2h  = (_Float16*)(ws + OFF_W2H);
  _Float16*  hbuf = (_Float16*)(ws + OFF_HB);
  _Float16*  w1rot= (_Float16*)(ws + OFF_W1R);
  float*     yrot = (float*)(ws + OFF_YR);

  prep_all<<<322, 256, 0, stream>>>(dx, h0, W1, Whh, b1, bhh, Wih, W4, b4, bih,
                                    W2, b2, hbuf, Wzh, bz, bc, WcT, w2h, bar);
  decoder_main<<<128, 256, 0, stream>>>(dx, xin, h0, W3, b3, Wfc, bfc,
                                        Wzh, bz, WcT, bc, w2h,
                                        hbuf, w1rot, yrot, bar, (float*)d_out);
}